// Round 11
// baseline (59.436 us; speedup 1.0000x reference)
//
#include <hip/hip_runtime.h>

#define B 16384
#define C 4
#define M 512
#define D 512
#define NCH 16
#define NSEG 64   // B/256 candidate segments
#define QSCALE 16777216.0f   // 2^24 fixed-point scale for deterministic atomics

// One emitted copy => bitwise-identical entropy in every kernel.
__device__ __noinline__ float entropyLab(float4 l, int* labOut)
{
    float m = l.x; int idx = 0;
    if (l.y > m) { m = l.y; idx = 1; }
    if (l.z > m) { m = l.z; idx = 2; }
    if (l.w > m) { m = l.w; idx = 3; }
    float e0 = expf(l.x - m), e1 = expf(l.y - m), e2 = expf(l.z - m), e3 = expf(l.w - m);
    float s = e0 + e1 + e2 + e3;
    float inv = 1.0f / s;
    float lse = logf(s);
    float ent = -(e0 * inv * (l.x - m - lse) + e1 * inv * (l.y - m - lse)
                + e2 * inv * (l.z - m - lse) + e3 * inv * (l.w - m - lse));
    *labOut = idx;
    return ent;
}

// ---------------- KA: recompute-staged pairwise ranks (partials, no atomics)
// grid (NSEG+8, NCH). Every block stages chunk y (segments 4y..4y+3) by
// recomputing candidates from logits. x<NSEG: partial ranks for segment x's
// candidates -> rnkB_part[y]. x>=NSEG: memo-row partials -> rnkM_part[y].
// y==0 additionally: out (pred+entropy), loArr, SQ zeroing.
__global__ __launch_bounds__(256) void kA_rank(
    const float* __restrict__ logits,
    const float* __restrict__ ent_memo,
    float* __restrict__ out,
    int* __restrict__ loArr,
    int* __restrict__ rnkB_part,
    int* __restrict__ rnkM_part,
    unsigned long long* __restrict__ SQ)
{
    __shared__ uint2 ch[1024];
    __shared__ int wsc[4];
    const int x = blockIdx.x, y = blockIdx.y, tid = threadIdx.x;
    const int lane = tid & 63, wv = tid >> 6;

    float am0 = ent_memo[M - 1],     am1 = ent_memo[2 * M - 1];
    float am2 = ent_memo[3 * M - 1], am3 = ent_memo[4 * M - 1];

    // ---- stage chunk y into LDS by recompute (no dependency on other blocks)
    int off = 0;
    for (int s4 = 0; s4 < 4; s4++) {
        int b = (4 * y + s4) * 256 + tid;
        float4 l = *reinterpret_cast<const float4*>(logits + (size_t)b * 4);
        int lab; float ent = entropyLab(l, &lab);
        float am = lab == 0 ? am0 : (lab == 1 ? am1 : (lab == 2 ? am2 : am3));
        bool flag = ent < am;
        unsigned long long mask = __ballot(flag);
        int prefix = __popcll(mask & ((1ull << lane) - 1ull));
        if (lane == 0) wsc[wv] = __popcll(mask);
        __syncthreads();
        int base = 0;
        for (int w = 0; w < wv; w++) base += wsc[w];
        int cnt = wsc[0] + wsc[1] + wsc[2] + wsc[3];
        if (flag)
            ch[off + base + prefix] =
                make_uint2(__float_as_uint(ent), ((unsigned)lab << 14) | (unsigned)b);
        off += cnt;
        __syncthreads();
    }
    const int total = off;

    if (x < NSEG) {
        // own segment: recompute, get compact slot, count partial rank
        int b = x * 256 + tid;
        float4 l = *reinterpret_cast<const float4*>(logits + (size_t)b * 4);
        int lab; float ent = entropyLab(l, &lab);
        float am = lab == 0 ? am0 : (lab == 1 ? am1 : (lab == 2 ? am2 : am3));
        bool flag = ent < am;
        unsigned long long mask = __ballot(flag);
        int prefix = __popcll(mask & ((1ull << lane) - 1ull));
        if (lane == 0) wsc[wv] = __popcll(mask);
        __syncthreads();
        int base = 0;
        for (int w = 0; w < wv; w++) base += wsc[w];
        int slot = base + prefix;

        if (flag) {
            int r = 0;
            for (int i = 0; i < total; i++) {
                uint2 w2 = ch[i];
                float e2 = __uint_as_float(w2.x);
                if ((int)((w2.y >> 14) & 3) == lab &&
                    (e2 < ent || (e2 == ent && (int)(w2.y & 0x3FFF) < b))) r++;
            }
            rnkB_part[y * B + x * 256 + slot] = r;   // unconditional when flag
        }
        if (y == 0) {
            // pred + entropy outputs
            float m2 = fmaxf(fmaxf(l.x, l.y), fmaxf(l.z, l.w));
            float e0 = expf(l.x - m2), e1 = expf(l.y - m2);
            float e2 = expf(l.z - m2), e3 = expf(l.w - m2);
            float inv = 1.0f / (e0 + e1 + e2 + e3);
            float4 pr = { e0 * inv, e1 * inv, e2 * inv, e3 * inv };
            *reinterpret_cast<float4*>(out + (size_t)B * 4 + (size_t)b * 4) = pr;
            out[(size_t)B * 8 + b] = ent;
            if (flag) {
                const float* Ac = ent_memo + (lab << 9);
                int l0 = 0, hi = M;              // upper_bound -> #{A <= ent}
                while (l0 < hi) { int mid = (l0 + hi) >> 1; if (Ac[mid] <= ent) l0 = mid + 1; else hi = mid; }
                loArr[x * 256 + slot] = l0;
            }
        }
    } else {
        int t = (x - NSEG) * 256 + tid;          // [0, C*M)
        float Am = ent_memo[t];
        int mc = t >> 9;
        int rm = 0;
        for (int i = 0; i < total; i++) {
            uint2 w2 = ch[i];
            if ((int)((w2.y >> 14) & 3) == mc && __uint_as_float(w2.x) < Am) rm++;
        }
        rnkM_part[y * (C * M) + t] = rm;         // unconditional
        if (y == 0) SQ[t] = 0ULL;
    }
}

// ---------------- KB: sum partials + flag-masked dense accumulate -> SQ ----
// blocks 0..511: batch, seg = x>>3, colchunk q = x&7 (64 cols).
// blocks 512..575: memo rowgroups. Deterministic int64 fixed-point atomics.
__global__ __launch_bounds__(256) void kB_acc(
    const float* __restrict__ logits,
    const float* __restrict__ ent_memo,
    const int* __restrict__ loArr,
    const int* __restrict__ rnkB_part,
    const int* __restrict__ rnkM_part,
    const float* __restrict__ text_memo,
    const float* __restrict__ text_embeds,
    unsigned long long* __restrict__ SQ)
{
    __shared__ int meta[256];
    __shared__ int wsc[4];
    const int x = blockIdx.x, tid = threadIdx.x;
    const int col0 = (x & 7) << 6;
    const int lane = tid & 63, sg = tid >> 6;

    if (x < 512) {
        const int seg = x >> 3;
        int b = seg * 256 + tid;
        float4 l = *reinterpret_cast<const float4*>(logits + (size_t)b * 4);
        int lab; float ent = entropyLab(l, &lab);
        float am = ent_memo[(lab << 9) + M - 1];
        bool flag = ent < am;
        unsigned long long mask = __ballot(flag);
        int prefix = __popcll(mask & ((1ull << lane) - 1ull));
        if (lane == 0) wsc[sg] = __popcll(mask);
        meta[tid] = 0;
        __syncthreads();
        int base = 0;
        for (int w = 0; w < sg; w++) base += wsc[w];
        if (flag) {
            int slot = base + prefix;
            int lo = loArr[seg * 256 + slot];
            int r = 0;
            #pragma unroll
            for (int yy = 0; yy < NCH; yy++) r += rnkB_part[yy * B + seg * 256 + slot];
            if (lo + r < M)
                meta[slot] = (int)((unsigned)lab | 4u | ((unsigned)(b & 0x3FFF) << 3));
        }
        __syncthreads();

        float a0 = 0.f, a1 = 0.f, a2 = 0.f, a3 = 0.f;
        #pragma unroll 8
        for (int k = 0; k < 64; k++) {
            int slot = (k << 2) | sg;               // wave-uniform
            int mt = meta[slot];
            int bidx = mt >> 3;
            float v = text_embeds[(size_t)bidx * D + col0 + lane]; // unkept -> row 0 (L2)
            bool kept = (mt & 4) != 0;
            int lb = mt & 3;
            a0 += (kept && lb == 0) ? v : 0.f;
            a1 += (kept && lb == 1) ? v : 0.f;
            a2 += (kept && lb == 2) ? v : 0.f;
            a3 += (kept && lb == 3) ? v : 0.f;
        }
        __shared__ float red[4][4][64];             // [sg][label][lane]
        red[sg][0][lane] = a0; red[sg][1][lane] = a1;
        red[sg][2][lane] = a2; red[sg][3][lane] = a3;
        __syncthreads();
        float t = ((red[0][sg][lane] + red[1][sg][lane])
                 + red[2][sg][lane]) + red[3][sg][lane];
        long long q = llrintf(t * QSCALE);
        atomicAdd(&SQ[(sg << 9) + col0 + lane], (unsigned long long)q);
    } else {
        const int g = (x - 512) >> 3;               // rowgroup 0..7
        const int c = g >> 1;                       // label
        const int base = g << 8;                    // first global memo row
        {
            int i = base + tid;
            int rm = 0;
            #pragma unroll
            for (int yy = 0; yy < NCH; yy++) rm += rnkM_part[yy * (C * M) + i];
            meta[tid] = ((i & (M - 1)) + rm < M) ? 1 : 0;
        }
        __syncthreads();
        float a = 0.f;
        #pragma unroll 8
        for (int k = 0; k < 64; k++) {
            int slot = (k << 2) | sg;
            float v = text_memo[(size_t)(base + slot) * D + col0 + lane];
            a += meta[slot] ? v : 0.f;
        }
        __shared__ float redm[4][64];
        redm[sg][lane] = a;
        __syncthreads();
        if (tid < 64) {
            float t = ((redm[0][tid] + redm[1][tid]) + redm[2][tid]) + redm[3][tid];
            long long q = llrintf(t * QSCALE);
            atomicAdd(&SQ[(c << 9) + col0 + tid], (unsigned long long)q);
        }
    }
}

// ---------------- KC: SQ->VGPR S + GEMV + combines + softmaxes -------------
__global__ __launch_bounds__(256) void kC_cosin(
    const unsigned long long* __restrict__ SQ,
    const float* __restrict__ text_embeds,
    float* __restrict__ out)
{
    const int tid = threadIdx.x;
    const int wave = tid >> 6, lane = tid & 63;
    const float sc = 1.0f / QSCALE;
    float s0[8], s1[8], s2[8], s3[8];
    #pragma unroll
    for (int j = 0; j < 8; j++) {
        s0[j] = (float)(long long)SQ[0 * 512 + lane * 8 + j] * sc;
        s1[j] = (float)(long long)SQ[1 * 512 + lane * 8 + j] * sc;
        s2[j] = (float)(long long)SQ[2 * 512 + lane * 8 + j] * sc;
        s3[j] = (float)(long long)SQ[3 * 512 + lane * 8 + j] * sc;
    }
    for (int r4 = 0; r4 < 4; r4++) {
        int b = blockIdx.x * 16 + wave * 4 + r4;
        const float4* te4 = reinterpret_cast<const float4*>(text_embeds + (size_t)b * D);
        float4 t0 = te4[lane * 2], t1 = te4[lane * 2 + 1];
        float te[8] = { t0.x, t0.y, t0.z, t0.w, t1.x, t1.y, t1.z, t1.w };
        float c0 = 0.f, c1 = 0.f, c2 = 0.f, c3 = 0.f;
        #pragma unroll
        for (int j = 0; j < 8; j++) {
            c0 += te[j] * s0[j];
            c1 += te[j] * s1[j];
            c2 += te[j] * s2[j];
            c3 += te[j] * s3[j];
        }
        for (int off = 32; off; off >>= 1) {
            c0 += __shfl_down(c0, off, 64);
            c1 += __shfl_down(c1, off, 64);
            c2 += __shfl_down(c2, off, 64);
            c3 += __shfl_down(c3, off, 64);
        }
        if (lane == 0) {
            float t0c = c0 + c2, t1c = c1 + c3;   // text_combine
            float v0c = c0 + c1, v1c = c2 + c3;   // vision_combine
            float tm = fmaxf(t0c, t1c);
            float te0 = expf(t0c - tm), te1 = expf(t1c - tm);
            float ts = te0 + te1;
            float mt0 = te0 / ts, mt1 = te1 / ts;
            float vm = fmaxf(v0c, v1c);
            float ve0 = expf(v0c - vm), ve1 = expf(v1c - vm);
            float vs = ve0 + ve1;
            float mv0 = ve0 / vs, mv1 = ve1 / vs;
            float4 o = { mt0 * mv0, mt1 * mv0, mt0 * mv1, mt1 * mv1 };
            *reinterpret_cast<float4*>(out + (size_t)b * 4) = o;
        }
    }
}

// ---------------------------------------------------------------------------
extern "C" void kernel_launch(void* const* d_in, const int* in_sizes, int n_in,
                              void* d_out, int out_size, void* d_ws, size_t ws_size,
                              hipStream_t stream)
{
    (void)in_sizes; (void)n_in; (void)out_size; (void)ws_size;
    const float* logits      = (const float*)d_in[0];
    const float* text_embeds = (const float*)d_in[1];
    const float* ent_memo    = (const float*)d_in[3];
    const float* text_memo   = (const float*)d_in[4];
    float* out = (float*)d_out;
    char* ws = (char*)d_ws;

    // workspace layout (bytes), 256-aligned; ws is ~256 MB so size is a non-issue
    int* loArr     = (int*)(ws + 0);           // 64 KB
    int* rnkB_part = (int*)(ws + 65536);       // NCH*B*4 = 1 MB   -> 1114112
    int* rnkM_part = (int*)(ws + 1114112);     // NCH*C*M*4 = 128 KB -> 1245184
    unsigned long long* SQ = (unsigned long long*)(ws + 1245184); // 16 KB

    kA_rank<<<dim3(NSEG + 8, NCH), 256, 0, stream>>>(
        logits, ent_memo, out, loArr, rnkB_part, rnkM_part, SQ);
    kB_acc<<<576, 256, 0, stream>>>(
        logits, ent_memo, loArr, rnkB_part, rnkM_part,
        text_memo, text_embeds, SQ);
    kC_cosin<<<1024, 256, 0, stream>>>(SQ, text_embeds, out);
}